// Round 4
// baseline (445.120 us; speedup 1.0000x reference)
//
#include <hip/hip_runtime.h>
#include <hip/hip_bf16.h>
#include <cstdint>

// Problem constants: B=8, L=4096, D=768, Y=2048
#define BB 8
#define LL 4096
#define DD 768
#define YY 2048

typedef unsigned short u16;
typedef __bf16 bf16x8 __attribute__((ext_vector_type(8)));
typedef __bf16 bf16x2 __attribute__((ext_vector_type(2)));
typedef float f32x16 __attribute__((ext_vector_type(16)));

__device__ __forceinline__ u16 f2bf(float f) {
    uint32_t u = __float_as_uint(f);
    u += 0x7fffu + ((u >> 16) & 1u);   // RNE
    return (u16)(u >> 16);
}

__device__ __forceinline__ uint32_t pkbf(float a, float b) {
#if __has_builtin(__builtin_amdgcn_cvt_pk_bf16_f32)
    bf16x2 p = __builtin_amdgcn_cvt_pk_bf16_f32(a, b);
    return __builtin_bit_cast(uint32_t, p);
#else
    return (uint32_t)f2bf(a) | ((uint32_t)f2bf(b) << 16);
#endif
}

#define GLL(src, dst) \
    __builtin_amdgcn_global_load_lds((const __attribute__((address_space(1))) unsigned int*)(src), \
                                     (__attribute__((address_space(3))) unsigned int*)(dst), 16, 0, 0)

// ---- single prologue kernel: cast x/U/fw to bf16 + zero rowsum/ynum/out ----
// (was 3 casts + 2 memsets = 5 launches; launch-gap overhead was ~40% of the
// non-fused time budget)
__global__ __launch_bounds__(256) void prep_k(const float* __restrict__ x,
                                              const float* __restrict__ Uw,
                                              const float* __restrict__ fw,
                                              u16* __restrict__ x16, u16* __restrict__ U16,
                                              u16* __restrict__ fw16,
                                              float* __restrict__ rz,   // rowsum+ynum (contig)
                                              float* __restrict__ out0) {
    const int id = blockIdx.x, t = threadIdx.x;
    const float* src; u16* dst; int i;
    if (id < 24576)      { i = id * 256 + t;           src = x;  dst = x16;  }
    else if (id < 26112) { i = (id - 24576) * 256 + t; src = Uw; dst = U16;  }
    else                 { i = (id - 26112) * 256 + t; src = fw; dst = fw16; }
    float4 v = ((const float4*)src)[i];
    uint2 h;
    h.x = pkbf(v.x, v.y); h.y = pkbf(v.z, v.w);
    ((uint2*)dst)[i] = h;
    if (id < 32) {                                   // 32*256 float4 = 32768 floats
        ((float4*)rz)[id * 256 + t] = make_float4(0.f, 0.f, 0.f, 0.f);
        if (id == 0 && t == 0) out0[0] = 0.f;
    }
}

// ---------------- FUSED kernel: S=U.x^T and G=fw.x^T, epilogue sum exp(S), exp(S)*G ------
// y[b,r] = sum_l exp(att[r,l]) * G[r,l] / rowsum[r]   (summation order swapped).
// R12 (best scaffold): 128l x 128y block, 4 waves (2x2), per-wave 64x64, BK=32, 3-buf,
// counted vmcnt(12), 2 blocks/CU -> 224 us, 921 TF eff.
// R13 (8-wave fine-phase): REGRESSED 245 us -- 4 barriers/tile with 1 block/CU = no
// cross-block fill at barriers; worse L2 order. Reverted.
// R14: keep R12 loop verbatim; switch MFMA 16x16x32 -> 32x32x16 (4096 vs 3277 FLOP/cyc,
// half the MFMA instructions, same 12 ds_read_b128/tile) with FRAGMENT-ORDER LDS:
// GLL dest linear (t*16B), global source pre-permuted so LDS holds MFMA fragments
// back-to-back; ds_read = frag_base + lane*16 (contiguous, conflict-free by construction).
// Frag layout (32x32x16 bf16): lane l holds row/col l&31, k=(l>>5)*8+j.
__global__ __launch_bounds__(256, 2) void fused_k(const u16* __restrict__ Xg, const u16* __restrict__ Ug,
                                                  const u16* __restrict__ Wg,
                                                  float* __restrict__ rowsum, float* __restrict__ ynum) {
    __shared__ u16 As[3 * 4096];      // x frags: 8 frags x 1KB per buf (3-buf, 24 KB)
    __shared__ u16 Us[3 * 4096];      // U frags (24 KB)
    __shared__ u16 Ws[3 * 4096];      // fw frags (24 KB)
    const int id = blockIdx.x;
    const int b = id & 7;             // batch pinned per XCD (%8 round-robin heuristic)
    const int r = id >> 3;            // 0..511
    const int yhalf = r >> 8;         // 0..1   (outer: U/fw half swapped once)
    const int q = r & 255;
    const int mblk = q >> 3;          // 0..31  (middle: x-tile advances, U/fw-half L2-hot)
    const int nblk = (yhalf << 3) + (q & 7);    // inner 8 y-blocks share one x-tile
    const u16* A = Xg + (size_t)b * LL * DD;
    rowsum += (size_t)b * YY;
    ynum   += (size_t)b * YY;
    const int m0 = mblk * 128;        // l
    const int n0 = nblk * 128;        // y
    const int t = threadIdx.x;
    const int lane = t & 63;
    const int w = t >> 6;             // wave 0..3
    const int wm = (w >> 1) * 64;     // l-offset of wave
    const int wn = (w & 1) * 64;      // y-offset of wave

    // staging sources, fragment order: GLL#0 writes frags F=w (rows (F>>1)*32..+31,
    // k-half F&1); GLL#1 writes frags F=w+4 (rows +64). lane l supplies
    // [row = M*32 + (l&31)][k = kh*16 + (l>>5)*8 .. +7]
    const int srow = ((w >> 1) << 5) + (lane & 31);
    const int skof = ((w & 1) << 4) + ((lane >> 5) << 3);
    const u16* Ab0 = A + (size_t)(m0 + srow) * DD + skof;        // l rows 0..63
    const u16* Ab1 = A + (size_t)(m0 + 64 + srow) * DD + skof;   // l rows 64..127
    const u16* Ub0 = Ug + (size_t)(n0 + srow) * DD + skof;       // y rows 0..63
    const u16* Ub1 = Ug + (size_t)(n0 + 64 + srow) * DD + skof;  // y rows 64..127
    const u16* Wb0 = Wg + (size_t)(n0 + srow) * DD + skof;
    const u16* Wb1 = Wg + (size_t)(n0 + 64 + srow) * DD + skof;
    const int c0 = t * 8, c1 = (t + 256) * 8;    // u16 idx: wave-uniform base + lane*16B

    f32x16 aS[2][2] = {};
    f32x16 aG[2][2] = {};
    // compute-side frag offsets (u16 idx): frag F at F*512; A: F=(wm/32+ms)*2+kh;
    // B: F=(wn/32+ns)*2+kh
    const int a0 = (w >> 1) * 2048 + lane * 8;
    const int b0 = (w & 1) * 2048 + lane * 8;

#define STAGE(bi)                                                       \
    {                                                                   \
        GLL(Ab0, As + (bi) * 4096 + c0);                                \
        GLL(Ab1, As + (bi) * 4096 + c1);                                \
        GLL(Ub0, Us + (bi) * 4096 + c0);                                \
        GLL(Ub1, Us + (bi) * 4096 + c1);                                \
        GLL(Wb0, Ws + (bi) * 4096 + c0);                                \
        GLL(Wb1, Ws + (bi) * 4096 + c1);                                \
        Ab0 += 32; Ab1 += 32; Ub0 += 32; Ub1 += 32; Wb0 += 32; Wb1 += 32; \
    }

#define M32(a, bb, c) __builtin_amdgcn_mfma_f32_32x32x16_bf16(a, bb, c, 0, 0, 0)

#define COMPUTE(p)                                                                  \
    {                                                                               \
        bf16x8 af[2][2], bu[2][2], bw[2][2];                                        \
        _Pragma("unroll") for (int ms = 0; ms < 2; ++ms)                            \
            _Pragma("unroll") for (int kh = 0; kh < 2; ++kh)                        \
                af[ms][kh] = *(const bf16x8*)(As + (p) + a0 + ms * 1024 + kh * 512);\
        _Pragma("unroll") for (int ns = 0; ns < 2; ++ns)                            \
            _Pragma("unroll") for (int kh = 0; kh < 2; ++kh) {                      \
                bu[ns][kh] = *(const bf16x8*)(Us + (p) + b0 + ns * 1024 + kh * 512);\
                bw[ns][kh] = *(const bf16x8*)(Ws + (p) + b0 + ns * 1024 + kh * 512);\
            }                                                                       \
        __builtin_amdgcn_s_setprio(1);                                              \
        _Pragma("unroll") for (int ms = 0; ms < 2; ++ms)                            \
            _Pragma("unroll") for (int ns = 0; ns < 2; ++ns) {                      \
                aS[ms][ns] = M32(af[ms][0], bu[ns][0], aS[ms][ns]);                 \
                aG[ms][ns] = M32(af[ms][0], bw[ns][0], aG[ms][ns]);                 \
                aS[ms][ns] = M32(af[ms][1], bu[ns][1], aS[ms][ns]);                 \
                aG[ms][ns] = M32(af[ms][1], bw[ns][1], aG[ms][ns]);                 \
            }                                                                       \
        __builtin_amdgcn_s_setprio(0);                                              \
    }

#define WAITV(n) asm volatile("s_waitcnt vmcnt(" #n ")" ::: "memory")
#define WAITL    asm volatile("s_waitcnt lgkmcnt(0)" ::: "memory")
#define BAR      __builtin_amdgcn_s_barrier()

    // prologue: tiles 0,1 in flight (12 outstanding GLLs per thread)
    STAGE(0)
    STAGE(1)

    // main loop: kt = 0..20 (7 x 3, buffers cycle 0,1,2; stage kt+2 each step).
    // WAITV(12): my 6 oldest outstanding loads (= tile kt) done; tiles kt+1,kt+2
    // stay in flight across both barriers.  B1: tile-kt data in LDS for all.
    // WAITL+B2: everyone's ds_reads of this buffer drained -> buffer free.
    for (int i = 0; i < 7; ++i) {
        STAGE(2) WAITV(12); BAR; COMPUTE(0)      WAITL; BAR;
        STAGE(0) WAITV(12); BAR; COMPUTE(4096)   WAITL; BAR;
        STAGE(1) WAITV(12); BAR; COMPUTE(8192)   WAITL; BAR;
    }
    // kt=21: last stage (tile 23 -> buf 2)
    STAGE(2) WAITV(12); BAR; COMPUTE(0)      WAITL; BAR;
    // kt=22: drain to 6 (tile 23 still in flight)
    WAITV(6); BAR; COMPUTE(4096)             WAITL; BAR;
    // kt=23: final tile
    WAITV(0); BAR; COMPUTE(8192)
#undef COMPUTE
#undef STAGE

    // epilogue (32x32 C/D: col = lane&31, rows = perm of 0..31 over (reg, lane>>5);
    // reduction over l is permutation-invariant -> only col mapping matters).
    // lane covers col y = n0+wn+ns*32+(lane&31); rows wm+ms*32+{16 regs x lane-half}.
    #pragma unroll
    for (int ns = 0; ns < 2; ++ns) {
        const int y = n0 + wn + ns * 32 + (lane & 31);
        float rs = 0.f, ys = 0.f;
        #pragma unroll
        for (int ms = 0; ms < 2; ++ms) {
            #pragma unroll
            for (int rr = 0; rr < 16; ++rr) {
                float e = __expf(aS[ms][ns][rr]);
                rs += e;
                ys += e * aG[ms][ns][rr];
            }
        }
        rs += __shfl_xor(rs, 32, 64);  ys += __shfl_xor(ys, 32, 64);
        if (lane < 32) {
            atomicAdd(&rowsum[y], rs);
            atomicAdd(&ynum[y], ys);
        }
    }
}

// -------- finalize: y = ynum/rowsum + bias (writeback), CE loss over y --------
// one block per batch; partial NLLs combined via atomicAdd into out0 (zeroed in prep)
__global__ __launch_bounds__(256) void ce_loss_k(const float* __restrict__ ynum,
                                                 const float* __restrict__ rowsum,
                                                 const float* __restrict__ fb,
                                                 const int* __restrict__ tgt,
                                                 float* __restrict__ out0,
                                                 float* __restrict__ yv) {
    __shared__ float smx[4], ssum[4], stv[4];
    const int b = blockIdx.x;
    const int t = threadIdx.x;
    const int wave = t >> 6, lane = t & 63;
    const float* yn = ynum + b * YY;
    const float* rsm = rowsum + b * YY;
    float* row = yv + b * YY;
    const int tg = tgt[b];
    float v[8];
    float mx = -3.0e38f;
    float tv = 0.f;
    #pragma unroll
    for (int i = 0; i < 8; ++i) {
        const int idx = t + 256 * i;
        v[i] = yn[idx] / rsm[idx] + fb[idx];
        row[idx] = v[i];                    // write final y
        mx = fmaxf(mx, v[i]);
        if (idx == tg) tv = v[i];
    }
    // block-reduce max
    #pragma unroll
    for (int o = 32; o; o >>= 1) mx = fmaxf(mx, __shfl_xor(mx, o, 64));
    if (lane == 0) smx[wave] = mx;
    __syncthreads();
    mx = fmaxf(fmaxf(smx[0], smx[1]), fmaxf(smx[2], smx[3]));
    float s = 0.f;
    #pragma unroll
    for (int i = 0; i < 8; ++i) s += __expf(v[i] - mx);
    #pragma unroll
    for (int o = 32; o; o >>= 1) { s += __shfl_xor(s, o, 64); tv += __shfl_xor(tv, o, 64); }
    if (lane == 0) { ssum[wave] = s; stv[wave] = tv; }
    __syncthreads();
    if (t == 0) {
        float st = ssum[0] + ssum[1] + ssum[2] + ssum[3];
        float tt = stv[0] + stv[1] + stv[2] + stv[3];
        atomicAdd(out0, (mx + logf(st) - tt) * 0.125f);
    }
}

extern "C" void kernel_launch(void* const* d_in, const int* in_sizes, int n_in,
                              void* d_out, int out_size, void* d_ws, size_t ws_size,
                              hipStream_t stream) {
    const float* x   = (const float*)d_in[0];   // (B,L,D)
    const float* Uw  = (const float*)d_in[1];   // (Y,D)
    const float* fw  = (const float*)d_in[2];   // (Y,D)
    const float* fb  = (const float*)d_in[3];   // (Y,)
    const int*   tgt = (const int*)d_in[4];     // (B,)
    float* out = (float*)d_out;                 // [loss, y(B*Y)]

    char* ws = (char*)d_ws;
    u16*  x16  = (u16*)(ws);                          // B*L*D bf16 = 50,331,648 B
    u16*  U16  = (u16*)(ws + 50331648);               // Y*D bf16   =  3,145,728 B
    u16*  fw16 = (u16*)(ws + 53477376);               // Y*D bf16   =  3,145,728 B
    float* rowsum = (float*)(ws + 56623104);          // B*Y fp32   =     65,536 B
    float* ynum   = (float*)(ws + 56688640);          // B*Y fp32   =     65,536 B

    // single prologue launch: casts + zero rowsum/ynum/out
    prep_k<<<27648, 256, 0, stream>>>(x, Uw, fw, x16, U16, fw16, rowsum, out);

    // Fused S/G GEMM + exp + reductions: 4096 blocks (128l x 128y tiles),
    // L2-resident-weights order (R12 mapping)
    fused_k<<<(LL / 128) * (YY / 128) * BB, 256, 0, stream>>>(x16, U16, fw16, rowsum, ynum);

    ce_loss_k<<<BB, 256, 0, stream>>>(ynum, rowsum, fb, tgt, out, out + 1);
}

// Round 5
// 390.313 us; speedup vs baseline: 1.1404x; 1.1404x over previous
//
#include <hip/hip_runtime.h>
#include <hip/hip_bf16.h>
#include <cstdint>

// Problem constants: B=8, L=4096, D=768, Y=2048
#define BB 8
#define LL 4096
#define DD 768
#define YY 2048

typedef unsigned short u16;
typedef __bf16 bf16x8 __attribute__((ext_vector_type(8)));
typedef __bf16 bf16x2 __attribute__((ext_vector_type(2)));
typedef float f32x16 __attribute__((ext_vector_type(16)));

__device__ __forceinline__ u16 f2bf(float f) {
    uint32_t u = __float_as_uint(f);
    u += 0x7fffu + ((u >> 16) & 1u);   // RNE
    return (u16)(u >> 16);
}

__device__ __forceinline__ uint32_t pkbf(float a, float b) {
#if __has_builtin(__builtin_amdgcn_cvt_pk_bf16_f32)
    bf16x2 p = __builtin_amdgcn_cvt_pk_bf16_f32(a, b);
    return __builtin_bit_cast(uint32_t, p);
#else
    return (uint32_t)f2bf(a) | ((uint32_t)f2bf(b) << 16);
#endif
}

#define GLL(src, dst) \
    __builtin_amdgcn_global_load_lds((const __attribute__((address_space(1))) unsigned int*)(src), \
                                     (__attribute__((address_space(3))) unsigned int*)(dst), 16, 0, 0)

// ---- single prologue kernel: cast x/U/fw to bf16 + zero rowsum/ynum/out ----
__global__ __launch_bounds__(256) void prep_k(const float* __restrict__ x,
                                              const float* __restrict__ Uw,
                                              const float* __restrict__ fw,
                                              u16* __restrict__ x16, u16* __restrict__ U16,
                                              u16* __restrict__ fw16,
                                              float* __restrict__ rz,   // rowsum+ynum (contig)
                                              float* __restrict__ out0) {
    const int id = blockIdx.x, t = threadIdx.x;
    const float* src; u16* dst; int i;
    if (id < 24576)      { i = id * 256 + t;           src = x;  dst = x16;  }
    else if (id < 26112) { i = (id - 24576) * 256 + t; src = Uw; dst = U16;  }
    else                 { i = (id - 26112) * 256 + t; src = fw; dst = fw16; }
    float4 v = ((const float4*)src)[i];
    uint2 h;
    h.x = pkbf(v.x, v.y); h.y = pkbf(v.z, v.w);
    ((uint2*)dst)[i] = h;
    if (id < 32) {                                   // 32*256 float4 = 32768 floats
        ((float4*)rz)[id * 256 + t] = make_float4(0.f, 0.f, 0.f, 0.f);
        if (id == 0 && t == 0) out0[0] = 0.f;
    }
}

// ---------------- FUSED kernel: S=U.x^T and G=fw.x^T, epilogue sum exp(S), exp(S)*G ------
// y[b,r] = sum_l exp(att[r,l]) * G[r,l] / rowsum[r]   (summation order swapped).
// R12 (scaffold, proven 224 us): 128l x 128y block, 4 waves (2x2), per-wave 64x64,
//   BK=32, 3-buf, counted vmcnt(12), row-major XOR-swizzled LDS, coalesced 64B/row GLL.
// R13 (8-wave fine-phase): REGRESSED -- 1 block/CU exposes every barrier. Reverted.
// R14 (32x32x16 + fragment-order LDS): REGRESSED -- frag-order staging scattered global
//   reads to 32B granules, 2x L1 transactions, GLL path request-rate-bound. Reverted.
// R15: R12 staging/layout VERBATIM + 32x32x16 MFMA (4060 vs 3377 FLOP/cyc, half the
//   MFMA instructions) via swizzle-matched per-lane ds_read addresses:
//   LDS slot (16B units) for (row, chunk c): s = row*4 + (c ^ ((row>>1)&3)).
//   32x32 A-frag: lane l needs row=l&31 (+ms*32), chunk=kh*2+(l>>5); consecutive-8-lane
//   groups span rows r..r+7 -> s&7 takes all 8 values -> conflict-free (as R12).
__global__ __launch_bounds__(256, 2) void fused_k(const u16* __restrict__ Xg, const u16* __restrict__ Ug,
                                                  const u16* __restrict__ Wg,
                                                  float* __restrict__ rowsum, float* __restrict__ ynum) {
    __shared__ u16 As[3 * 4096];      // x tile: 128 l-rows x 32 k (3-buf, 24 KB)
    __shared__ u16 Us[3 * 4096];      // U tile: 128 y-rows x 32 k (3-buf, 24 KB)
    __shared__ u16 Ws[3 * 4096];      // fw tile (24 KB)
    const int id = blockIdx.x;
    const int b = id & 7;             // batch pinned per XCD (%8 round-robin heuristic)
    const int r = id >> 3;            // 0..511
    const int yhalf = r >> 8;         // 0..1   (outer: U/fw half swapped once)
    const int q = r & 255;
    const int mblk = q >> 3;          // 0..31  (middle: x-tile advances, U/fw-half L2-hot)
    const int nblk = (yhalf << 3) + (q & 7);    // inner 8 y-blocks share one x-tile
    const u16* A = Xg + (size_t)b * LL * DD;
    rowsum += (size_t)b * YY;
    ynum   += (size_t)b * YY;
    const int m0 = mblk * 128;        // l
    const int n0 = nblk * 128;        // y
    const int t = threadIdx.x;
    const int lane = t & 63;
    const int w = t >> 6;             // wave 0..3
    const int wm = (w >> 1) * 64;     // l-offset of wave
    const int wn = (w & 1) * 64;      // y-offset of wave

    // ---- staging (R12 verbatim): row t>>2, stored chunk pos t&3 holds actual chunk
    // (t&3)^((t>>3)&3); 64B contiguous per row-visit, 16 rows per GLL instr.
    const int kq0 = (t & 3) ^ ((t >> 3) & 3);
    const u16* Ab0 = A + (size_t)(m0 + (t >> 2)) * DD + kq0 * 8;       // l rows 0..63
    const u16* Ab1 = A + (size_t)(m0 + (t >> 2) + 64) * DD + kq0 * 8;  // l rows 64..127
    const u16* Ub0 = Ug + (size_t)(n0 + (t >> 2)) * DD + kq0 * 8;      // y rows 0..63
    const u16* Ub1 = Ug + (size_t)(n0 + (t >> 2) + 64) * DD + kq0 * 8; // y rows 64..127
    const u16* Wb0 = Wg + (size_t)(n0 + (t >> 2)) * DD + kq0 * 8;
    const u16* Wb1 = Wg + (size_t)(n0 + (t >> 2) + 64) * DD + kq0 * 8;
    const int c0 = t * 8, c1 = (t + 256) * 8;

    f32x16 aS[2][2] = {};
    f32x16 aG[2][2] = {};

    // ---- compute-side 32x32-fragment read addresses against the swizzled layout
    const int l31 = lane & 31;
    const int lh  = lane >> 5;                 // k-half within 16-k frag
    const int xm  = (l31 >> 1) & 3;            // (row>>1)&3 (wm, ms*32 vanish mod 4)
    const int ar  = (wm + l31) * 32;           // A row base (u16); +ms*1024 per ms
    const int br  = (wn + l31) * 32;           // B row base
    const int ck0 = (lh ^ xm) * 8;             // kh=0: chunk 0/1 swizzled pos (u16)
    const int ck1 = ((2 + lh) ^ xm) * 8;       // kh=1: chunk 2/3

#define STAGE(bi)                                                       \
    {                                                                   \
        GLL(Ab0, As + (bi) * 4096 + c0);                                \
        GLL(Ab1, As + (bi) * 4096 + c1);                                \
        GLL(Ub0, Us + (bi) * 4096 + c0);                                \
        GLL(Ub1, Us + (bi) * 4096 + c1);                                \
        GLL(Wb0, Ws + (bi) * 4096 + c0);                                \
        GLL(Wb1, Ws + (bi) * 4096 + c1);                                \
        Ab0 += 32; Ab1 += 32; Ub0 += 32; Ub1 += 32; Wb0 += 32; Wb1 += 32; \
    }

#define M32(a, bb, c) __builtin_amdgcn_mfma_f32_32x32x16_bf16(a, bb, c, 0, 0, 0)

#define COMPUTE(p)                                                                  \
    {                                                                               \
        bf16x8 af[2][2], bu[2][2], bw[2][2];                                        \
        _Pragma("unroll") for (int ms = 0; ms < 2; ++ms) {                          \
            af[ms][0] = *(const bf16x8*)(As + (p) + ar + ms * 1024 + ck0);          \
            af[ms][1] = *(const bf16x8*)(As + (p) + ar + ms * 1024 + ck1);          \
        }                                                                           \
        _Pragma("unroll") for (int ns = 0; ns < 2; ++ns) {                          \
            bu[ns][0] = *(const bf16x8*)(Us + (p) + br + ns * 1024 + ck0);          \
            bu[ns][1] = *(const bf16x8*)(Us + (p) + br + ns * 1024 + ck1);          \
            bw[ns][0] = *(const bf16x8*)(Ws + (p) + br + ns * 1024 + ck0);          \
            bw[ns][1] = *(const bf16x8*)(Ws + (p) + br + ns * 1024 + ck1);          \
        }                                                                           \
        __builtin_amdgcn_s_setprio(1);                                              \
        _Pragma("unroll") for (int ms = 0; ms < 2; ++ms)                            \
            _Pragma("unroll") for (int ns = 0; ns < 2; ++ns) {                      \
                aS[ms][ns] = M32(af[ms][0], bu[ns][0], aS[ms][ns]);                 \
                aG[ms][ns] = M32(af[ms][0], bw[ns][0], aG[ms][ns]);                 \
            }                                                                       \
        _Pragma("unroll") for (int ms = 0; ms < 2; ++ms)                            \
            _Pragma("unroll") for (int ns = 0; ns < 2; ++ns) {                      \
                aS[ms][ns] = M32(af[ms][1], bu[ns][1], aS[ms][ns]);                 \
                aG[ms][ns] = M32(af[ms][1], bw[ns][1], aG[ms][ns]);                 \
            }                                                                       \
        __builtin_amdgcn_s_setprio(0);                                              \
    }

#define WAITV(n) asm volatile("s_waitcnt vmcnt(" #n ")" ::: "memory")
#define WAITL    asm volatile("s_waitcnt lgkmcnt(0)" ::: "memory")
#define BAR      __builtin_amdgcn_s_barrier()

    // prologue: tiles 0,1 in flight (12 outstanding GLLs per thread)
    STAGE(0)
    STAGE(1)

    // main loop: kt = 0..20 (7 x 3, buffers cycle 0,1,2; stage kt+2 each step).
    // WAITV(12): my 6 oldest outstanding loads (= tile kt) done; tiles kt+1,kt+2
    // stay in flight across both barriers.  B1: tile-kt data in LDS for all.
    // WAITL+B2: everyone's ds_reads of this buffer drained -> buffer free.
    for (int i = 0; i < 7; ++i) {
        STAGE(2) WAITV(12); BAR; COMPUTE(0)      WAITL; BAR;
        STAGE(0) WAITV(12); BAR; COMPUTE(4096)   WAITL; BAR;
        STAGE(1) WAITV(12); BAR; COMPUTE(8192)   WAITL; BAR;
    }
    // kt=21: last stage (tile 23 -> buf 2)
    STAGE(2) WAITV(12); BAR; COMPUTE(0)      WAITL; BAR;
    // kt=22: drain to 6 (tile 23 still in flight)
    WAITV(6); BAR; COMPUTE(4096)             WAITL; BAR;
    // kt=23: final tile
    WAITV(0); BAR; COMPUTE(8192)
#undef COMPUTE
#undef STAGE

    // epilogue (32x32 C/D: col = lane&31 = y; rows = permutation of the 32 l-values
    // across (reg, lane>>5) -- reduction over l is permutation-invariant).
    #pragma unroll
    for (int ns = 0; ns < 2; ++ns) {
        const int y = n0 + wn + ns * 32 + l31;
        float rs = 0.f, ys = 0.f;
        #pragma unroll
        for (int ms = 0; ms < 2; ++ms) {
            #pragma unroll
            for (int rr = 0; rr < 16; ++rr) {
                float e = __expf(aS[ms][ns][rr]);
                rs += e;
                ys += e * aG[ms][ns][rr];
            }
        }
        rs += __shfl_xor(rs, 32, 64);  ys += __shfl_xor(ys, 32, 64);
        if (lh == 0) {
            atomicAdd(&rowsum[y], rs);
            atomicAdd(&ynum[y], ys);
        }
    }
}

// -------- finalize: y = ynum/rowsum + bias (writeback), CE loss over y --------
// one block per batch; partial NLLs combined via atomicAdd into out0 (zeroed in prep)
__global__ __launch_bounds__(256) void ce_loss_k(const float* __restrict__ ynum,
                                                 const float* __restrict__ rowsum,
                                                 const float* __restrict__ fb,
                                                 const int* __restrict__ tgt,
                                                 float* __restrict__ out0,
                                                 float* __restrict__ yv) {
    __shared__ float smx[4], ssum[4], stv[4];
    const int b = blockIdx.x;
    const int t = threadIdx.x;
    const int wave = t >> 6, lane = t & 63;
    const float* yn = ynum + b * YY;
    const float* rsm = rowsum + b * YY;
    float* row = yv + b * YY;
    const int tg = tgt[b];
    float v[8];
    float mx = -3.0e38f;
    float tv = 0.f;
    #pragma unroll
    for (int i = 0; i < 8; ++i) {
        const int idx = t + 256 * i;
        v[i] = yn[idx] / rsm[idx] + fb[idx];
        row[idx] = v[i];                    // write final y
        mx = fmaxf(mx, v[i]);
        if (idx == tg) tv = v[i];
    }
    // block-reduce max
    #pragma unroll
    for (int o = 32; o; o >>= 1) mx = fmaxf(mx, __shfl_xor(mx, o, 64));
    if (lane == 0) smx[wave] = mx;
    __syncthreads();
    mx = fmaxf(fmaxf(smx[0], smx[1]), fmaxf(smx[2], smx[3]));
    float s = 0.f;
    #pragma unroll
    for (int i = 0; i < 8; ++i) s += __expf(v[i] - mx);
    #pragma unroll
    for (int o = 32; o; o >>= 1) { s += __shfl_xor(s, o, 64); tv += __shfl_xor(tv, o, 64); }
    if (lane == 0) { ssum[wave] = s; stv[wave] = tv; }
    __syncthreads();
    if (t == 0) {
        float st = ssum[0] + ssum[1] + ssum[2] + ssum[3];
        float tt = stv[0] + stv[1] + stv[2] + stv[3];
        atomicAdd(out0, (mx + logf(st) - tt) * 0.125f);
    }
}

extern "C" void kernel_launch(void* const* d_in, const int* in_sizes, int n_in,
                              void* d_out, int out_size, void* d_ws, size_t ws_size,
                              hipStream_t stream) {
    const float* x   = (const float*)d_in[0];   // (B,L,D)
    const float* Uw  = (const float*)d_in[1];   // (Y,D)
    const float* fw  = (const float*)d_in[2];   // (Y,D)
    const float* fb  = (const float*)d_in[3];   // (Y,)
    const int*   tgt = (const int*)d_in[4];     // (B,)
    float* out = (float*)d_out;                 // [loss, y(B*Y)]

    char* ws = (char*)d_ws;
    u16*  x16  = (u16*)(ws);                          // B*L*D bf16 = 50,331,648 B
    u16*  U16  = (u16*)(ws + 50331648);               // Y*D bf16   =  3,145,728 B
    u16*  fw16 = (u16*)(ws + 53477376);               // Y*D bf16   =  3,145,728 B
    float* rowsum = (float*)(ws + 56623104);          // B*Y fp32   =     65,536 B
    float* ynum   = (float*)(ws + 56688640);          // B*Y fp32   =     65,536 B

    // single prologue launch: casts + zero rowsum/ynum/out
    prep_k<<<27648, 256, 0, stream>>>(x, Uw, fw, x16, U16, fw16, rowsum, out);

    // Fused S/G GEMM + exp + reductions: 4096 blocks (128l x 128y tiles),
    // L2-resident-weights order (R12 mapping)
    fused_k<<<(LL / 128) * (YY / 128) * BB, 256, 0, stream>>>(x16, U16, fw16, rowsum, ynum);

    ce_loss_k<<<BB, 256, 0, stream>>>(ynum, rowsum, fb, tgt, out, out + 1);
}

// Round 6
// 370.447 us; speedup vs baseline: 1.2016x; 1.0536x over previous
//
#include <hip/hip_runtime.h>
#include <hip/hip_bf16.h>
#include <cstdint>

// Problem constants: B=8, L=4096, D=768, Y=2048
#define BB 8
#define LL 4096
#define DD 768
#define YY 2048

typedef unsigned short u16;
typedef __bf16 bf16x8 __attribute__((ext_vector_type(8)));
typedef __bf16 bf16x2 __attribute__((ext_vector_type(2)));
typedef float f32x16 __attribute__((ext_vector_type(16)));

__device__ __forceinline__ u16 f2bf(float f) {
    uint32_t u = __float_as_uint(f);
    u += 0x7fffu + ((u >> 16) & 1u);   // RNE
    return (u16)(u >> 16);
}

__device__ __forceinline__ uint32_t pkbf(float a, float b) {
#if __has_builtin(__builtin_amdgcn_cvt_pk_bf16_f32)
    bf16x2 p = __builtin_amdgcn_cvt_pk_bf16_f32(a, b);
    return __builtin_bit_cast(uint32_t, p);
#else
    return (uint32_t)f2bf(a) | ((uint32_t)f2bf(b) << 16);
#endif
}

#define GLL(src, dst) \
    __builtin_amdgcn_global_load_lds((const __attribute__((address_space(1))) unsigned int*)(src), \
                                     (__attribute__((address_space(3))) unsigned int*)(dst), 16, 0, 0)

// ---- prologue: cast x/U/fw to bf16 in TILED layout + zero rowsum/ynum/out ----
// Tiled bf16 layout (R16): 32-row panels, chunk-major within panel:
//   addr(row, d) = (row>>5)*24576 + (d>>3)*256 + (row&31)*8 + (d&7)   [u16]
// This makes (a) fused GLL staging read contiguous 1KB/wave, (b) LDS chunk-major,
// (c) 32x32x16 fragment ds_reads fully lane-linear (empirically 0-conflict class).
// Transpose via padded LDS tile: coalesced float4 in, coalesced 8B out.
__global__ __launch_bounds__(256) void prep_k(const float* __restrict__ x,
                                              const float* __restrict__ Uw,
                                              const float* __restrict__ fw,
                                              u16* __restrict__ x16, u16* __restrict__ U16,
                                              u16* __restrict__ fw16,
                                              float* __restrict__ rz,   // rowsum+ynum (contig)
                                              float* __restrict__ out0) {
    __shared__ u16 lds[32 * 34];                 // 32 rows x 32 u16, stride 34 (17 dw, odd)
    const int id = blockIdx.x, t = threadIdx.x;
    const float* src; u16* dst; int tile;
    if (id < 24576)      { tile = id;          src = x;  dst = x16;  }   // 1024 panels x 24
    else if (id < 26112) { tile = id - 24576;  src = Uw; dst = U16;  }   // 64 panels x 24
    else                 { tile = id - 26112;  src = fw; dst = fw16; }
    const int rt = tile / 24, dt = tile % 24;    // row-panel, d-tile (32 d each)
    const float* in = src + (size_t)rt * 32 * DD + dt * 32;
    // phase 1: read 32x32 floats (coalesced float4), cvt, store to padded LDS
    {
        const int r = t >> 3, dq = (t & 7) * 4;
        float4 v = *(const float4*)(in + (size_t)r * DD + dq);
        u16* p = &lds[r * 34 + dq];
        *(uint32_t*)(p)     = pkbf(v.x, v.y);
        *(uint32_t*)(p + 2) = pkbf(v.z, v.w);
    }
    __syncthreads();
    // phase 2: write chunk-major: out u16 idx t*4 == c*256 + r*8 + half*4
    {
        const int c = t >> 6, r = (t >> 1) & 31, half = t & 1;
        const u16* p = &lds[r * 34 + c * 8 + half * 4];
        uint2 o;
        o.x = *(const uint32_t*)(p);
        o.y = *(const uint32_t*)(p + 2);
        *(uint2*)(dst + (size_t)rt * 24576 + dt * 1024 + t * 4) = o;
    }
    if (id < 32) {                               // zero rowsum+ynum (32768 floats) + loss
        ((float4*)rz)[id * 256 + t] = make_float4(0.f, 0.f, 0.f, 0.f);
        if (id == 0 && t == 0) out0[0] = 0.f;
    }
}

// ---------------- FUSED kernel: S=U.x^T and G=fw.x^T, epilogue sum exp(S), exp(S)*G ------
// y[b,r] = sum_l exp(att[r,l]) * G[r,l] / rowsum[r]   (summation order swapped).
// R12 (scaffold, 224 us): 128l x 128y block, 4 waves 2x2, per-wave 64x64, BK=32, 3-buf,
//   counted vmcnt(12), 2 blocks/CU, 16x16x32 MFMA, contiguous-1KB swizzled reads, 0 confl.
// R15 (32x32x16, swizzle-matched strided reads): 1.9e7 bank conflicts (+4 cyc/read) ->
//   244 us. Empirical law from R12/R14/R15: wave b128 reads must be FULLY LANE-LINEAR
//   (or R12's exact contiguous-1KB pattern) to be conflict-free; my slot&7 model is
//   insufficient.
// R16: pre-tiled global layout (see prep_k) -> LDS chunk-major [rb][c][r]:
//   u16 off = rb*1024 + c*256 + r*8. Frag read (32x32x16, kh-half): base + lane*8 --
//   fully linear. GLL staging: contiguous 1KB/wave global -> linear LDS. No swizzle.
//   MFMA count halved vs R12 (16 vs 32 per tile), same 12 ds_read + 6 GLL per tile.
__global__ __launch_bounds__(256, 2) void fused_k(const u16* __restrict__ Xg, const u16* __restrict__ Ug,
                                                  const u16* __restrict__ Wg,
                                                  float* __restrict__ rowsum, float* __restrict__ ynum) {
    __shared__ u16 As[3 * 4096];      // x tile: 128 l x 32 k, chunk-major (3-buf, 24 KB)
    __shared__ u16 Us[3 * 4096];      // U tile (24 KB)
    __shared__ u16 Ws[3 * 4096];      // fw tile (24 KB)
    const int id = blockIdx.x;
    const int b = id & 7;             // batch pinned per XCD (%8 round-robin heuristic)
    const int r = id >> 3;            // 0..511
    const int yhalf = r >> 8;         // 0..1   (outer: U/fw half swapped once)
    const int q = r & 255;
    const int mblk = q >> 3;          // 0..31  (middle: x-tile advances, U/fw-half L2-hot)
    const int nblk = (yhalf << 3) + (q & 7);    // inner 8 y-blocks share one x-tile
    const u16* A = Xg + (size_t)b * LL * DD;    // panel-major: b offset = b*128 panels
    rowsum += (size_t)b * YY;
    ynum   += (size_t)b * YY;
    const int m0 = mblk * 128;        // l
    const int n0 = nblk * 128;        // y
    const int t = threadIdx.x;
    const int lane = t & 63;
    const int w = t >> 6;             // wave 0..3
    const int wm = (w >> 1) * 64;     // l-offset of wave
    const int wn = (w & 1) * 64;      // y-offset of wave

    // ---- staging sources (tiled global): dest slot s=t (c0) / s=t+256 (c1) holds
    // (rb=s>>7, c=(s>>5)&3, r=s&31); source = panel(base + rb)*24576 + c*256 + r*8.
    // Per-wave: 1KB fully contiguous global read.
    const int sc = ((t >> 5) & 3) * 256 + (t & 31) * 8;
    const u16* Ab0 = A + (size_t)((m0 >> 5) + (t >> 7)) * 24576 + sc;       // l rows 0..63
    const u16* Ab1 = Ab0 + 2 * 24576;                                        // l rows 64..127
    const u16* Ub0 = Ug + (size_t)((n0 >> 5) + (t >> 7)) * 24576 + sc;      // y rows 0..63
    const u16* Ub1 = Ub0 + 2 * 24576;                                        // y rows 64..127
    const u16* Wb0 = Wg + (size_t)((n0 >> 5) + (t >> 7)) * 24576 + sc;
    const u16* Wb1 = Wb0 + 2 * 24576;
    const int c0 = t * 8, c1 = (t + 256) * 8;

    f32x16 aS[2][2] = {};
    f32x16 aG[2][2] = {};

    // ---- compute-side fragment reads: fully lane-linear.
    // af[ms][kh] at rb=(wm>>5)+ms: off = rb*1024 + kh*512 + lane*8
    //   (lane l -> slot rb*128 + (kh*2+(l>>5))*32 + (l&31) = row l&31, k=(kh*2+l>>5)*8+j)
    const int a0 = (wm >> 5) * 1024 + lane * 8;
    const int b0 = (wn >> 5) * 1024 + lane * 8;
    const int l31 = lane & 31;
    const int lh  = lane >> 5;

#define STAGE(bi)                                                       \
    {                                                                   \
        GLL(Ab0, As + (bi) * 4096 + c0);                                \
        GLL(Ab1, As + (bi) * 4096 + c1);                                \
        GLL(Ub0, Us + (bi) * 4096 + c0);                                \
        GLL(Ub1, Us + (bi) * 4096 + c1);                                \
        GLL(Wb0, Ws + (bi) * 4096 + c0);                                \
        GLL(Wb1, Ws + (bi) * 4096 + c1);                                \
        Ab0 += 1024; Ab1 += 1024; Ub0 += 1024; Ub1 += 1024;             \
        Wb0 += 1024; Wb1 += 1024;                                       \
    }

#define M32(a, bb, c) __builtin_amdgcn_mfma_f32_32x32x16_bf16(a, bb, c, 0, 0, 0)

#define COMPUTE(p)                                                                  \
    {                                                                               \
        bf16x8 af[2][2], bu[2][2], bw[2][2];                                        \
        _Pragma("unroll") for (int ms = 0; ms < 2; ++ms) {                          \
            af[ms][0] = *(const bf16x8*)(As + (p) + a0 + ms * 1024);                \
            af[ms][1] = *(const bf16x8*)(As + (p) + a0 + ms * 1024 + 512);          \
        }                                                                           \
        _Pragma("unroll") for (int ns = 0; ns < 2; ++ns) {                          \
            bu[ns][0] = *(const bf16x8*)(Us + (p) + b0 + ns * 1024);                \
            bu[ns][1] = *(const bf16x8*)(Us + (p) + b0 + ns * 1024 + 512);          \
            bw[ns][0] = *(const bf16x8*)(Ws + (p) + b0 + ns * 1024);                \
            bw[ns][1] = *(const bf16x8*)(Ws + (p) + b0 + ns * 1024 + 512);          \
        }                                                                           \
        __builtin_amdgcn_s_setprio(1);                                              \
        _Pragma("unroll") for (int ms = 0; ms < 2; ++ms)                            \
            _Pragma("unroll") for (int ns = 0; ns < 2; ++ns) {                      \
                aS[ms][ns] = M32(af[ms][0], bu[ns][0], aS[ms][ns]);                 \
                aG[ms][ns] = M32(af[ms][0], bw[ns][0], aG[ms][ns]);                 \
            }                                                                       \
        _Pragma("unroll") for (int ms = 0; ms < 2; ++ms)                            \
            _Pragma("unroll") for (int ns = 0; ns < 2; ++ns) {                      \
                aS[ms][ns] = M32(af[ms][1], bu[ns][1], aS[ms][ns]);                 \
                aG[ms][ns] = M32(af[ms][1], bw[ns][1], aG[ms][ns]);                 \
            }                                                                       \
        __builtin_amdgcn_s_setprio(0);                                              \
    }

#define WAITV(n) asm volatile("s_waitcnt vmcnt(" #n ")" ::: "memory")
#define WAITL    asm volatile("s_waitcnt lgkmcnt(0)" ::: "memory")
#define BAR      __builtin_amdgcn_s_barrier()

    // prologue: tiles 0,1 in flight (12 outstanding GLLs per thread)
    STAGE(0)
    STAGE(1)

    // main loop: kt = 0..20 (7 x 3, buffers cycle 0,1,2; stage kt+2 each step).
    // WAITV(12): my 6 oldest outstanding loads (= tile kt) done; tiles kt+1,kt+2
    // stay in flight across both barriers.  B1: tile-kt data in LDS for all.
    // WAITL+B2: everyone's ds_reads of this buffer drained -> buffer free.
    for (int i = 0; i < 7; ++i) {
        STAGE(2) WAITV(12); BAR; COMPUTE(0)      WAITL; BAR;
        STAGE(0) WAITV(12); BAR; COMPUTE(4096)   WAITL; BAR;
        STAGE(1) WAITV(12); BAR; COMPUTE(8192)   WAITL; BAR;
    }
    // kt=21: last stage (tile 23 -> buf 2)
    STAGE(2) WAITV(12); BAR; COMPUTE(0)      WAITL; BAR;
    // kt=22: drain to 6 (tile 23 still in flight)
    WAITV(6); BAR; COMPUTE(4096)             WAITL; BAR;
    // kt=23: final tile
    WAITV(0); BAR; COMPUTE(8192)
#undef COMPUTE
#undef STAGE

    // epilogue (32x32 C/D: col = lane&31 = y; rows = permutation of the 32 l-values
    // across (reg, lane>>5) -- reduction over l is permutation-invariant).
    // Verified by R15's passing refcheck.
    #pragma unroll
    for (int ns = 0; ns < 2; ++ns) {
        const int y = n0 + wn + ns * 32 + l31;
        float rs = 0.f, ys = 0.f;
        #pragma unroll
        for (int ms = 0; ms < 2; ++ms) {
            #pragma unroll
            for (int rr = 0; rr < 16; ++rr) {
                float e = __expf(aS[ms][ns][rr]);
                rs += e;
                ys += e * aG[ms][ns][rr];
            }
        }
        rs += __shfl_xor(rs, 32, 64);  ys += __shfl_xor(ys, 32, 64);
        if (lh == 0) {
            atomicAdd(&rowsum[y], rs);
            atomicAdd(&ynum[y], ys);
        }
    }
}

// -------- finalize: y = ynum/rowsum + bias (writeback), CE loss over y --------
// one block per batch; partial NLLs combined via atomicAdd into out0 (zeroed in prep)
__global__ __launch_bounds__(256) void ce_loss_k(const float* __restrict__ ynum,
                                                 const float* __restrict__ rowsum,
                                                 const float* __restrict__ fb,
                                                 const int* __restrict__ tgt,
                                                 float* __restrict__ out0,
                                                 float* __restrict__ yv) {
    __shared__ float smx[4], ssum[4], stv[4];
    const int b = blockIdx.x;
    const int t = threadIdx.x;
    const int wave = t >> 6, lane = t & 63;
    const float* yn = ynum + b * YY;
    const float* rsm = rowsum + b * YY;
    float* row = yv + b * YY;
    const int tg = tgt[b];
    float v[8];
    float mx = -3.0e38f;
    float tv = 0.f;
    #pragma unroll
    for (int i = 0; i < 8; ++i) {
        const int idx = t + 256 * i;
        v[i] = yn[idx] / rsm[idx] + fb[idx];
        row[idx] = v[i];                    // write final y
        mx = fmaxf(mx, v[i]);
        if (idx == tg) tv = v[i];
    }
    // block-reduce max
    #pragma unroll
    for (int o = 32; o; o >>= 1) mx = fmaxf(mx, __shfl_xor(mx, o, 64));
    if (lane == 0) smx[wave] = mx;
    __syncthreads();
    mx = fmaxf(fmaxf(smx[0], smx[1]), fmaxf(smx[2], smx[3]));
    float s = 0.f;
    #pragma unroll
    for (int i = 0; i < 8; ++i) s += __expf(v[i] - mx);
    #pragma unroll
    for (int o = 32; o; o >>= 1) { s += __shfl_xor(s, o, 64); tv += __shfl_xor(tv, o, 64); }
    if (lane == 0) { ssum[wave] = s; stv[wave] = tv; }
    __syncthreads();
    if (t == 0) {
        float st = ssum[0] + ssum[1] + ssum[2] + ssum[3];
        float tt = stv[0] + stv[1] + stv[2] + stv[3];
        atomicAdd(out0, (mx + logf(st) - tt) * 0.125f);
    }
}

extern "C" void kernel_launch(void* const* d_in, const int* in_sizes, int n_in,
                              void* d_out, int out_size, void* d_ws, size_t ws_size,
                              hipStream_t stream) {
    const float* x   = (const float*)d_in[0];   // (B,L,D)
    const float* Uw  = (const float*)d_in[1];   // (Y,D)
    const float* fw  = (const float*)d_in[2];   // (Y,D)
    const float* fb  = (const float*)d_in[3];   // (Y,)
    const int*   tgt = (const int*)d_in[4];     // (B,)
    float* out = (float*)d_out;                 // [loss, y(B*Y)]

    char* ws = (char*)d_ws;
    u16*  x16  = (u16*)(ws);                          // B*L*D bf16 = 50,331,648 B (tiled)
    u16*  U16  = (u16*)(ws + 50331648);               // Y*D bf16   =  3,145,728 B (tiled)
    u16*  fw16 = (u16*)(ws + 53477376);               // Y*D bf16   =  3,145,728 B (tiled)
    float* rowsum = (float*)(ws + 56623104);          // B*Y fp32   =     65,536 B
    float* ynum   = (float*)(ws + 56688640);          // B*Y fp32   =     65,536 B

    // single prologue launch: tiled casts + zero rowsum/ynum/out
    prep_k<<<27648, 256, 0, stream>>>(x, Uw, fw, x16, U16, fw16, rowsum, out);

    // Fused S/G GEMM + exp + reductions: 4096 blocks (128l x 128y tiles),
    // L2-resident-weights order (R12 mapping)
    fused_k<<<(LL / 128) * (YY / 128) * BB, 256, 0, stream>>>(x16, U16, fw16, rowsum, ynum);

    ce_loss_k<<<BB, 256, 0, stream>>>(ynum, rowsum, fb, tgt, out, out + 1);
}

// Round 7
// 368.536 us; speedup vs baseline: 1.2078x; 1.0052x over previous
//
#include <hip/hip_runtime.h>
#include <hip/hip_bf16.h>
#include <cstdint>

// Problem constants: B=8, L=4096, D=768, Y=2048
#define BB 8
#define LL 4096
#define DD 768
#define YY 2048

typedef unsigned short u16;
typedef __bf16 bf16x8 __attribute__((ext_vector_type(8)));
typedef __bf16 bf16x2 __attribute__((ext_vector_type(2)));
typedef float f32x16 __attribute__((ext_vector_type(16)));

__device__ __forceinline__ u16 f2bf(float f) {
    uint32_t u = __float_as_uint(f);
    u += 0x7fffu + ((u >> 16) & 1u);   // RNE
    return (u16)(u >> 16);
}

__device__ __forceinline__ uint32_t pkbf(float a, float b) {
#if __has_builtin(__builtin_amdgcn_cvt_pk_bf16_f32)
    bf16x2 p = __builtin_amdgcn_cvt_pk_bf16_f32(a, b);
    return __builtin_bit_cast(uint32_t, p);
#else
    return (uint32_t)f2bf(a) | ((uint32_t)f2bf(b) << 16);
#endif
}

#define GLL(src, dst) \
    __builtin_amdgcn_global_load_lds((const __attribute__((address_space(1))) unsigned int*)(src), \
                                     (__attribute__((address_space(3))) unsigned int*)(dst), 16, 0, 0)

// ---- prologue: cast x/U/fw to bf16 in TILED layout + zero rowsum/ynum/out ----
// Tiled bf16 layout: 32-row panels, chunk-major within panel:
//   addr(row, d) = (row>>5)*24576 + (d>>3)*256 + (row&31)*8 + (d&7)   [u16]
// (a) fused GLL staging reads contiguous 1KB/wave, (b) 32x32x16 fragment reads --
// from LDS or DIRECTLY from global -- are fully lane-linear / contiguous 1KB/wave.
__global__ __launch_bounds__(256) void prep_k(const float* __restrict__ x,
                                              const float* __restrict__ Uw,
                                              const float* __restrict__ fw,
                                              u16* __restrict__ x16, u16* __restrict__ U16,
                                              u16* __restrict__ fw16,
                                              float* __restrict__ rz,   // rowsum+ynum (contig)
                                              float* __restrict__ out0) {
    __shared__ u16 lds[32 * 34];                 // 32 rows x 32 u16, stride 34 (17 dw, odd)
    const int id = blockIdx.x, t = threadIdx.x;
    const float* src; u16* dst; int tile;
    if (id < 24576)      { tile = id;          src = x;  dst = x16;  }   // 1024 panels x 24
    else if (id < 26112) { tile = id - 24576;  src = Uw; dst = U16;  }   // 64 panels x 24
    else                 { tile = id - 26112;  src = fw; dst = fw16; }
    const int rt = tile / 24, dt = tile % 24;    // row-panel, d-tile (32 d each)
    const float* in = src + (size_t)rt * 32 * DD + dt * 32;
    // phase 1: read 32x32 floats (coalesced float4), cvt, store to padded LDS
    {
        const int r = t >> 3, dq = (t & 7) * 4;
        float4 v = *(const float4*)(in + (size_t)r * DD + dq);
        u16* p = &lds[r * 34 + dq];
        *(uint32_t*)(p)     = pkbf(v.x, v.y);
        *(uint32_t*)(p + 2) = pkbf(v.z, v.w);
    }
    __syncthreads();
    // phase 2: write chunk-major: out u16 idx t*4 == c*256 + r*8 + half*4
    {
        const int c = t >> 6, r = (t >> 1) & 31, half = t & 1;
        const u16* p = &lds[r * 34 + c * 8 + half * 4];
        uint2 o;
        o.x = *(const uint32_t*)(p);
        o.y = *(const uint32_t*)(p + 2);
        *(uint2*)(dst + (size_t)rt * 24576 + dt * 1024 + t * 4) = o;
    }
    if (id < 32) {                               // zero rowsum+ynum (32768 floats) + loss
        ((float4*)rz)[id * 256 + t] = make_float4(0.f, 0.f, 0.f, 0.f);
        if (id == 0 && t == 0) out0[0] = 0.f;
    }
}

// ---------------- FUSED kernel: S=U.x^T and G=fw.x^T, epilogue sum exp(S), exp(S)*G ------
// y[b,r] = sum_l exp(att[r,l]) * G[r,l] / rowsum[r]   (summation order swapped).
// R16 (207 us, MfmaUtil 46, 0 conflicts): tiled-global layout, 32x32x16 MFMA, all three
//   operands through LDS. Pipe budget per block-tile pair: MFMA ~1024 cyc, LDS ~1630 cyc
//   -> LDS pipe is the binding resource.
// R17: U/W bypass LDS entirely. Weights are L2-resident (block order) and the tiled
//   layout makes a 32x32x16 B-fragment CONTIGUOUS 1KB/wave in global -> direct
//   global->reg loads, perfectly coalesced (fixes R14's scatter failure). LDS keeps
//   only A (HBM stream, 2x in-block reuse): 2-buf 16 KB, GLL staging, __syncthreads
//   2-phase (R11: drain ~= counted on this scaffold). Double-buffered U/W reg sets
//   give loads a full-tile latency window. LDS/pair 1630 -> ~540 cyc; MFMA-dominant.
__global__ __launch_bounds__(256, 2) void fused_k(const u16* __restrict__ Xg, const u16* __restrict__ Ug,
                                                  const u16* __restrict__ Wg,
                                                  float* __restrict__ rowsum, float* __restrict__ ynum) {
    __shared__ u16 As[2 * 4096];      // x tile: 128 l x 32 k, chunk-major (2-buf, 16 KB)
    const int id = blockIdx.x;
    const int b = id & 7;             // batch pinned per XCD (%8 round-robin heuristic)
    const int r = id >> 3;            // 0..511
    const int yhalf = r >> 8;         // 0..1   (outer: U/fw half swapped once)
    const int q = r & 255;
    const int mblk = q >> 3;          // 0..31  (middle: x-tile advances, U/fw-half L2-hot)
    const int nblk = (yhalf << 3) + (q & 7);    // inner 8 y-blocks share one x-tile
    const u16* A = Xg + (size_t)b * LL * DD;    // b offset = b*128 panels
    rowsum += (size_t)b * YY;
    ynum   += (size_t)b * YY;
    const int m0 = mblk * 128;        // l
    const int n0 = nblk * 128;        // y
    const int t = threadIdx.x;
    const int lane = t & 63;
    const int w = t >> 6;             // wave 0..3
    const int wm = (w >> 1) * 64;     // l-offset of wave
    const int wn = (w & 1) * 64;      // y-offset of wave
    const int l31 = lane & 31;
    const int lh  = lane >> 5;

    // ---- A staging (R16 verbatim): dest slot s=t (c0) / s=t+256 (c1) holds
    // (rb=s>>7, c=(s>>5)&3, r=s&31); per-wave 1KB contiguous global read.
    const int sc = ((t >> 5) & 3) * 256 + (t & 31) * 8;
    const u16* Ab0 = A + (size_t)((m0 >> 5) + (t >> 7)) * 24576 + sc;       // l rows 0..63
    const u16* Ab1 = Ab0 + 2 * 24576;                                        // l rows 64..127
    const int c0 = t * 8, c1 = (t + 256) * 8;

    // ---- A fragment reads from LDS: fully lane-linear
    const int a0 = (wm >> 5) * 1024 + lane * 8;

    // ---- U/W direct from global (L2): per (ns,kh) fragment = contiguous 1KB/wave.
    // u16 addr = panel((n0+wn)>>5 + ns)*24576 + chunk(kt*4 + kh*2 + lh)*256 + l31*8
    const u16* Ud = Ug + (size_t)((n0 + wn) >> 5) * 24576 + lh * 256 + l31 * 8;
    const u16* Wd = Wg + (size_t)((n0 + wn) >> 5) * 24576 + lh * 256 + l31 * 8;

    f32x16 aS[2][2] = {};
    f32x16 aG[2][2] = {};
    bf16x8 bu0[2][2], bw0[2][2], bu1[2][2], bw1[2][2];

#define STAGEA(bi)                                                      \
    {                                                                   \
        GLL(Ab0, As + (bi) * 4096 + c0);                                \
        GLL(Ab1, As + (bi) * 4096 + c1);                                \
        Ab0 += 1024; Ab1 += 1024;                                       \
    }

// load U/W K-tile at byte-offset OFF (u16 units: 0 / 1024 / 2048) into reg set SET
#define LOADUW(SET, OFF)                                                            \
    {                                                                               \
        _Pragma("unroll") for (int ns = 0; ns < 2; ++ns)                            \
            _Pragma("unroll") for (int kh = 0; kh < 2; ++kh) {                      \
                bu##SET[ns][kh] = *(const bf16x8*)(Ud + ns * 24576 + (OFF) + kh * 512); \
                bw##SET[ns][kh] = *(const bf16x8*)(Wd + ns * 24576 + (OFF) + kh * 512); \
            }                                                                       \
    }

#define M32(a, bb, c) __builtin_amdgcn_mfma_f32_32x32x16_bf16(a, bb, c, 0, 0, 0)

#define COMPUTE(p, SET)                                                             \
    {                                                                               \
        bf16x8 af[2][2];                                                            \
        _Pragma("unroll") for (int ms = 0; ms < 2; ++ms) {                          \
            af[ms][0] = *(const bf16x8*)(As + (p) + a0 + ms * 1024);                \
            af[ms][1] = *(const bf16x8*)(As + (p) + a0 + ms * 1024 + 512);          \
        }                                                                           \
        __builtin_amdgcn_s_setprio(1);                                              \
        _Pragma("unroll") for (int ms = 0; ms < 2; ++ms)                            \
            _Pragma("unroll") for (int ns = 0; ns < 2; ++ns) {                      \
                aS[ms][ns] = M32(af[ms][0], bu##SET[ns][0], aS[ms][ns]);            \
                aG[ms][ns] = M32(af[ms][0], bw##SET[ns][0], aG[ms][ns]);            \
            }                                                                       \
        _Pragma("unroll") for (int ms = 0; ms < 2; ++ms)                            \
            _Pragma("unroll") for (int ns = 0; ns < 2; ++ns) {                      \
                aS[ms][ns] = M32(af[ms][1], bu##SET[ns][1], aS[ms][ns]);            \
                aG[ms][ns] = M32(af[ms][1], bw##SET[ns][1], aG[ms][ns]);            \
            }                                                                       \
        __builtin_amdgcn_s_setprio(0);                                              \
    }

    // prologue: stage A tile0 -> buf0, load U/W tile0 -> set0
    STAGEA(0)
    LOADUW(0, 0)
    __syncthreads();

    // 24 K-tiles, 2 per iteration. Each tile: stage/load NEXT tile, compute CURRENT.
    // __syncthreads() both releases the A buffer and drains GLL+global loads.
    for (int kt2 = 0; kt2 < 12; ++kt2) {
        // tile 2k: compute buf0/set0; prefetch tile 2k+1 (A->buf1, U/W->set1)
        STAGEA(1)
        LOADUW(1, 1024)
        COMPUTE(0, 0)
        __syncthreads();
        // tile 2k+1: compute buf1/set1; prefetch tile 2k+2 (A->buf0, U/W->set0)
        if (kt2 < 11) {
            STAGEA(0)
            LOADUW(0, 2048)
        }
        COMPUTE(4096, 1)
        __syncthreads();
        Ud += 2048; Wd += 2048;
    }
#undef COMPUTE
#undef STAGEA
#undef LOADUW

    // epilogue (32x32 C/D: col = lane&31 = y; rows = permutation of the 32 l-values
    // across (reg, lane>>5) -- reduction over l is permutation-invariant).
    // Verified by R15/R16 refcheck.
    #pragma unroll
    for (int ns = 0; ns < 2; ++ns) {
        const int y = n0 + wn + ns * 32 + l31;
        float rs = 0.f, ys = 0.f;
        #pragma unroll
        for (int ms = 0; ms < 2; ++ms) {
            #pragma unroll
            for (int rr = 0; rr < 16; ++rr) {
                float e = __expf(aS[ms][ns][rr]);
                rs += e;
                ys += e * aG[ms][ns][rr];
            }
        }
        rs += __shfl_xor(rs, 32, 64);  ys += __shfl_xor(ys, 32, 64);
        if (lh == 0) {
            atomicAdd(&rowsum[y], rs);
            atomicAdd(&ynum[y], ys);
        }
    }
}

// -------- finalize: y = ynum/rowsum + bias (writeback), CE loss over y --------
// one block per batch; partial NLLs combined via atomicAdd into out0 (zeroed in prep)
__global__ __launch_bounds__(256) void ce_loss_k(const float* __restrict__ ynum,
                                                 const float* __restrict__ rowsum,
                                                 const float* __restrict__ fb,
                                                 const int* __restrict__ tgt,
                                                 float* __restrict__ out0,
                                                 float* __restrict__ yv) {
    __shared__ float smx[4], ssum[4], stv[4];
    const int b = blockIdx.x;
    const int t = threadIdx.x;
    const int wave = t >> 6, lane = t & 63;
    const float* yn = ynum + b * YY;
    const float* rsm = rowsum + b * YY;
    float* row = yv + b * YY;
    const int tg = tgt[b];
    float v[8];
    float mx = -3.0e38f;
    float tv = 0.f;
    #pragma unroll
    for (int i = 0; i < 8; ++i) {
        const int idx = t + 256 * i;
        v[i] = yn[idx] / rsm[idx] + fb[idx];
        row[idx] = v[i];                    // write final y
        mx = fmaxf(mx, v[i]);
        if (idx == tg) tv = v[i];
    }
    // block-reduce max
    #pragma unroll
    for (int o = 32; o; o >>= 1) mx = fmaxf(mx, __shfl_xor(mx, o, 64));
    if (lane == 0) smx[wave] = mx;
    __syncthreads();
    mx = fmaxf(fmaxf(smx[0], smx[1]), fmaxf(smx[2], smx[3]));
    float s = 0.f;
    #pragma unroll
    for (int i = 0; i < 8; ++i) s += __expf(v[i] - mx);
    #pragma unroll
    for (int o = 32; o; o >>= 1) { s += __shfl_xor(s, o, 64); tv += __shfl_xor(tv, o, 64); }
    if (lane == 0) { ssum[wave] = s; stv[wave] = tv; }
    __syncthreads();
    if (t == 0) {
        float st = ssum[0] + ssum[1] + ssum[2] + ssum[3];
        float tt = stv[0] + stv[1] + stv[2] + stv[3];
        atomicAdd(out0, (mx + logf(st) - tt) * 0.125f);
    }
}

extern "C" void kernel_launch(void* const* d_in, const int* in_sizes, int n_in,
                              void* d_out, int out_size, void* d_ws, size_t ws_size,
                              hipStream_t stream) {
    const float* x   = (const float*)d_in[0];   // (B,L,D)
    const float* Uw  = (const float*)d_in[1];   // (Y,D)
    const float* fw  = (const float*)d_in[2];   // (Y,D)
    const float* fb  = (const float*)d_in[3];   // (Y,)
    const int*   tgt = (const int*)d_in[4];     // (B,)
    float* out = (float*)d_out;                 // [loss, y(B*Y)]

    char* ws = (char*)d_ws;
    u16*  x16  = (u16*)(ws);                          // B*L*D bf16 = 50,331,648 B (tiled)
    u16*  U16  = (u16*)(ws + 50331648);               // Y*D bf16   =  3,145,728 B (tiled)
    u16*  fw16 = (u16*)(ws + 53477376);               // Y*D bf16   =  3,145,728 B (tiled)
    float* rowsum = (float*)(ws + 56623104);          // B*Y fp32   =     65,536 B
    float* ynum   = (float*)(ws + 56688640);          // B*Y fp32   =     65,536 B

    // single prologue launch: tiled casts + zero rowsum/ynum/out
    prep_k<<<27648, 256, 0, stream>>>(x, Uw, fw, x16, U16, fw16, rowsum, out);

    // Fused S/G GEMM + exp + reductions: 4096 blocks (128l x 128y tiles),
    // L2-resident-weights order (R12 mapping)
    fused_k<<<(LL / 128) * (YY / 128) * BB, 256, 0, stream>>>(x16, U16, fw16, rowsum, ynum);

    ce_loss_k<<<BB, 256, 0, stream>>>(ynum, rowsum, fb, tgt, out, out + 1);
}

// Round 9
// 362.963 us; speedup vs baseline: 1.2264x; 1.0154x over previous
//
#include <hip/hip_runtime.h>
#include <hip/hip_bf16.h>
#include <cstdint>

// Problem constants: B=8, L=4096, D=768, Y=2048
#define BB 8
#define LL 4096
#define DD 768
#define YY 2048

typedef unsigned short u16;
typedef __bf16 bf16x8 __attribute__((ext_vector_type(8)));
typedef __bf16 bf16x2 __attribute__((ext_vector_type(2)));
typedef float f32x16 __attribute__((ext_vector_type(16)));

__device__ __forceinline__ u16 f2bf(float f) {
    uint32_t u = __float_as_uint(f);
    u += 0x7fffu + ((u >> 16) & 1u);   // RNE
    return (u16)(u >> 16);
}

__device__ __forceinline__ uint32_t pkbf(float a, float b) {
#if __has_builtin(__builtin_amdgcn_cvt_pk_bf16_f32)
    bf16x2 p = __builtin_amdgcn_cvt_pk_bf16_f32(a, b);
    return __builtin_bit_cast(uint32_t, p);
#else
    return (uint32_t)f2bf(a) | ((uint32_t)f2bf(b) << 16);
#endif
}

#define GLL(src, dst) \
    __builtin_amdgcn_global_load_lds((const __attribute__((address_space(1))) unsigned int*)(src), \
                                     (__attribute__((address_space(3))) unsigned int*)(dst), 16, 0, 0)

// ---- prologue: cast x/U/fw to bf16 in TILED layout + zero rowsum/ynum/out ----
// Tiled bf16 layout: 32-row panels, chunk-major within panel:
//   addr(row, d) = (row>>5)*24576 + (d>>3)*256 + (row&31)*8 + (d&7)   [u16]
// (a) fused GLL staging reads contiguous 1KB/wave, (b) 32x32x16 fragment reads --
// from LDS or DIRECTLY from global -- are fully lane-linear / contiguous 1KB/wave.
__global__ __launch_bounds__(256) void prep_k(const float* __restrict__ x,
                                              const float* __restrict__ Uw,
                                              const float* __restrict__ fw,
                                              u16* __restrict__ x16, u16* __restrict__ U16,
                                              u16* __restrict__ fw16,
                                              float* __restrict__ rz,   // rowsum+ynum (contig)
                                              float* __restrict__ out0) {
    __shared__ u16 lds[32 * 34];                 // 32 rows x 32 u16, stride 34 (17 dw, odd)
    const int id = blockIdx.x, t = threadIdx.x;
    const float* src; u16* dst; int tile;
    if (id < 24576)      { tile = id;          src = x;  dst = x16;  }   // 1024 panels x 24
    else if (id < 26112) { tile = id - 24576;  src = Uw; dst = U16;  }   // 64 panels x 24
    else                 { tile = id - 26112;  src = fw; dst = fw16; }
    const int rt = tile / 24, dt = tile % 24;    // row-panel, d-tile (32 d each)
    const float* in = src + (size_t)rt * 32 * DD + dt * 32;
    // phase 1: read 32x32 floats (coalesced float4), cvt, store to padded LDS
    {
        const int r = t >> 3, dq = (t & 7) * 4;
        float4 v = *(const float4*)(in + (size_t)r * DD + dq);
        u16* p = &lds[r * 34 + dq];
        *(uint32_t*)(p)     = pkbf(v.x, v.y);
        *(uint32_t*)(p + 2) = pkbf(v.z, v.w);
    }
    __syncthreads();
    // phase 2: write chunk-major: out u16 idx t*4 == c*256 + r*8 + half*4
    {
        const int c = t >> 6, r = (t >> 1) & 31, half = t & 1;
        const u16* p = &lds[r * 34 + c * 8 + half * 4];
        uint2 o;
        o.x = *(const uint32_t*)(p);
        o.y = *(const uint32_t*)(p + 2);
        *(uint2*)(dst + (size_t)rt * 24576 + dt * 1024 + t * 4) = o;
    }
    if (id < 32) {                               // zero rowsum+ynum (32768 floats) + loss
        ((float4*)rz)[id * 256 + t] = make_float4(0.f, 0.f, 0.f, 0.f);
        if (id == 0 && t == 0) out0[0] = 0.f;
    }
}

// ---------------- FUSED kernel: S=U.x^T and G=fw.x^T, epilogue sum exp(S), exp(S)*G ------
// y[b,r] = sum_l exp(att[r,l]) * G[r,l] / rowsum[r]   (summation order swapped).
// R16 (207 us, MfmaUtil 46, 0 conflicts): all operands via LDS; LDS pipe ~1630 cyc/pair
//   vs MFMA 1024 -> LDS-bound.
// R17 (U/W->reg via plain C loads): REGRESSED 225 us, VGPR=116 -- compiler SANK the
//   const-memory loads past __syncthreads to save registers (legal), killing prefetch.
// R18: loads forced with inline-asm global_load_dwordx4 (volatile = unsinkable, dest
//   regs pinned live). COMPILE FAIL: LOADUW(S?0:1) token-pasting garbage.
// R19: R18 with literal set indices threaded through TILE(P, CS, LS, NV).
//   Counted vmcnt ledger (issue order per tile: UW(kt+1) x8 THEN A-GLL(kt+2) x2):
//   WAITV(12) leaves A(kt+1)2 + UW(kt+1)8 + A(kt+2)2 in flight.
//   sched_barrier(0) after every waitcnt (rule 18). 2 UW reg sets, 3 A bufs,
//   6-tile unroll (LCM), static indices only. LDS/pair 1630 -> ~510 cyc.
__global__ __launch_bounds__(256, 2) void fused_k(const u16* __restrict__ Xg, const u16* __restrict__ Ug,
                                                  const u16* __restrict__ Wg,
                                                  float* __restrict__ rowsum, float* __restrict__ ynum) {
    __shared__ u16 As[3 * 4096];      // x tile: 128 l x 32 k, chunk-major (3-buf, 24 KB)
    const int id = blockIdx.x;
    const int b = id & 7;             // batch pinned per XCD (%8 round-robin heuristic)
    const int r = id >> 3;            // 0..511
    const int yhalf = r >> 8;         // 0..1   (outer: U/fw half swapped once)
    const int q = r & 255;
    const int mblk = q >> 3;          // 0..31  (middle: x-tile advances, U/fw-half L2-hot)
    const int nblk = (yhalf << 3) + (q & 7);    // inner 8 y-blocks share one x-tile
    const u16* A = Xg + (size_t)b * LL * DD;    // b offset = b*128 panels
    rowsum += (size_t)b * YY;
    ynum   += (size_t)b * YY;
    const int m0 = mblk * 128;        // l
    const int n0 = nblk * 128;        // y
    const int t = threadIdx.x;
    const int lane = t & 63;
    const int w = t >> 6;             // wave 0..3
    const int wm = (w >> 1) * 64;     // l-offset of wave
    const int wn = (w & 1) * 64;      // y-offset of wave
    const int l31 = lane & 31;
    const int lh  = lane >> 5;

    // ---- A staging: dest slot s=t (c0) / s=t+256 (c1) holds (rb=s>>7, c=(s>>5)&3,
    // r=s&31); per-wave 1KB contiguous global read.
    const int sc = ((t >> 5) & 3) * 256 + (t & 31) * 8;
    const u16* Ab0 = A + (size_t)((m0 >> 5) + (t >> 7)) * 24576 + sc;       // l rows 0..63
    const u16* Ab1 = Ab0 + 2 * 24576;                                        // l rows 64..127
    const int c0 = t * 8, c1 = (t + 256) * 8;

    // ---- A fragment reads from LDS: fully lane-linear
    const int a0 = (wm >> 5) * 1024 + lane * 8;

    // ---- U/W direct from global (L2): per (ns,kh) fragment = contiguous 1KB/wave.
    // u16 addr = panel((n0+wn)>>5 + ns)*24576 + chunk(kt*4 + kh*2 + lh)*256 + l31*8
    const u16* Ud  = Ug + (size_t)((n0 + wn) >> 5) * 24576 + lh * 256 + l31 * 8;
    const u16* Udp = Ud + 24576;
    const u16* Wd  = Wg + (size_t)((n0 + wn) >> 5) * 24576 + lh * 256 + l31 * 8;
    const u16* Wdp = Wd + 24576;

    f32x16 aS[2][2] = {};
    f32x16 aG[2][2] = {};
    bf16x8 bu0[2][2], bw0[2][2], bu1[2][2], bw1[2][2];

// inline-asm 16B global load: volatile = not sinkable/CSE-able; offset imm in BYTES
#define GLD(dst, p, IMM) \
    asm volatile("global_load_dwordx4 %0, %1, off offset:" #IMM : "=v"(dst) : "v"(p))

// load U/W K-tile into reg set SET (literal 0/1!); advance pointers by one K-tile
#define LOADUW(SET)                                                     \
    {                                                                   \
        GLD(bu##SET[0][0], Ud,  0);  GLD(bu##SET[0][1], Ud,  1024);     \
        GLD(bu##SET[1][0], Udp, 0);  GLD(bu##SET[1][1], Udp, 1024);     \
        GLD(bw##SET[0][0], Wd,  0);  GLD(bw##SET[0][1], Wd,  1024);     \
        GLD(bw##SET[1][0], Wdp, 0);  GLD(bw##SET[1][1], Wdp, 1024);     \
        Ud += 1024; Udp += 1024; Wd += 1024; Wdp += 1024;               \
    }

#define STAGEA(bi)                                                      \
    {                                                                   \
        GLL(Ab0, As + (bi) * 4096 + c0);                                \
        GLL(Ab1, As + (bi) * 4096 + c1);                                \
        Ab0 += 1024; Ab1 += 1024;                                       \
    }

#define M32(a, bb, c) __builtin_amdgcn_mfma_f32_32x32x16_bf16(a, bb, c, 0, 0, 0)

#define COMPUTE(p, SET)                                                             \
    {                                                                               \
        bf16x8 af[2][2];                                                            \
        _Pragma("unroll") for (int ms = 0; ms < 2; ++ms) {                          \
            af[ms][0] = *(const bf16x8*)(As + (p) + a0 + ms * 1024);                \
            af[ms][1] = *(const bf16x8*)(As + (p) + a0 + ms * 1024 + 512);          \
        }                                                                           \
        __builtin_amdgcn_s_setprio(1);                                              \
        _Pragma("unroll") for (int ms = 0; ms < 2; ++ms)                            \
            _Pragma("unroll") for (int ns = 0; ns < 2; ++ns) {                      \
                aS[ms][ns] = M32(af[ms][0], bu##SET[ns][0], aS[ms][ns]);            \
                aG[ms][ns] = M32(af[ms][0], bw##SET[ns][0], aG[ms][ns]);            \
            }                                                                       \
        _Pragma("unroll") for (int ms = 0; ms < 2; ++ms)                            \
            _Pragma("unroll") for (int ns = 0; ns < 2; ++ns) {                      \
                aS[ms][ns] = M32(af[ms][1], bu##SET[ns][1], aS[ms][ns]);            \
                aG[ms][ns] = M32(af[ms][1], bw##SET[ns][1], aG[ms][ns]);            \
            }                                                                       \
        __builtin_amdgcn_s_setprio(0);                                              \
    }

#define WAITV(n) asm volatile("s_waitcnt vmcnt(" #n ")" ::: "memory"); \
                 __builtin_amdgcn_sched_barrier(0)
#define WAITL    asm volatile("s_waitcnt lgkmcnt(0)" ::: "memory")
#define BAR      __builtin_amdgcn_s_barrier()

// one K-tile: issue UW(kt+1) into set LS, stage A(kt+2); wait; compute buf P, set CS.
// CS/LS are LITERAL 0/1 (token-pasted into reg-set names).
#define TILE(P, CS, LS, NV)                                             \
    LOADUW(LS)                                                          \
    STAGEA((P + 2) % 3)                                                 \
    WAITV(NV); BAR;                                                     \
    COMPUTE((P) * 4096, CS)                                             \
    WAITL; BAR;

    // prologue: A(0)->buf0, UW(0)->set0, A(1)->buf1.  Wait A(0)+UW(0): leave A(1)'s 2.
    STAGEA(0)
    LOADUW(0)
    STAGEA(1)
    WAITV(2); BAR;

    // tiles 0..17: 3 x 6-tile unroll (buf kt%3, compute set kt&1, load set ~kt&1).
    // Steady WAITV(12): completes UW(kt) [+ older]; leaves A(kt+1)2 + UW(kt+1)8 +
    // A(kt+2)2 in flight across both barriers.
    for (int g = 0; g < 3; ++g) {
        TILE(0, 0, 1, 12)
        TILE(1, 1, 0, 12)
        TILE(2, 0, 1, 12)
        TILE(0, 1, 0, 12)
        TILE(1, 0, 1, 12)
        TILE(2, 1, 0, 12)
    }
    // tiles 18..21: full bodies
    TILE(0, 0, 1, 12)
    TILE(1, 1, 0, 12)
    TILE(2, 0, 1, 12)
    TILE(0, 1, 0, 12)
    // tile 22: load UW(23) only (no A left); need UW(22): leave A(23)2+UW(23)8
    LOADUW(1)
    WAITV(10); BAR;
    COMPUTE(1 * 4096, 0)
    WAITL; BAR;
    // tile 23: need everything
    WAITV(0); BAR;
    COMPUTE(2 * 4096, 1)
#undef TILE
#undef COMPUTE
#undef STAGEA
#undef LOADUW
#undef GLD

    // epilogue (32x32 C/D: col = lane&31 = y; rows = permutation of the 32 l-values
    // across (reg, lane>>5) -- reduction over l is permutation-invariant).
    // Verified by R15/R16 refcheck.
    #pragma unroll
    for (int ns = 0; ns < 2; ++ns) {
        const int y = n0 + wn + ns * 32 + l31;
        float rs = 0.f, ys = 0.f;
        #pragma unroll
        for (int ms = 0; ms < 2; ++ms) {
            #pragma unroll
            for (int rr = 0; rr < 16; ++rr) {
                float e = __expf(aS[ms][ns][rr]);
                rs += e;
                ys += e * aG[ms][ns][rr];
            }
        }
        rs += __shfl_xor(rs, 32, 64);  ys += __shfl_xor(ys, 32, 64);
        if (lh == 0) {
            atomicAdd(&rowsum[y], rs);
            atomicAdd(&ynum[y], ys);
        }
    }
}

// -------- finalize: y = ynum/rowsum + bias (writeback), CE loss over y --------
// one block per batch; partial NLLs combined via atomicAdd into out0 (zeroed in prep)
__global__ __launch_bounds__(256) void ce_loss_k(const float* __restrict__ ynum,
                                                 const float* __restrict__ rowsum,
                                                 const float* __restrict__ fb,
                                                 const int* __restrict__ tgt,
                                                 float* __restrict__ out0,
                                                 float* __restrict__ yv) {
    __shared__ float smx[4], ssum[4], stv[4];
    const int b = blockIdx.x;
    const int t = threadIdx.x;
    const int wave = t >> 6, lane = t & 63;
    const float* yn = ynum + b * YY;
    const float* rsm = rowsum + b * YY;
    float* row = yv + b * YY;
    const int tg = tgt[b];
    float v[8];
    float mx = -3.0e38f;
    float tv = 0.f;
    #pragma unroll
    for (int i = 0; i < 8; ++i) {
        const int idx = t + 256 * i;
        v[i] = yn[idx] / rsm[idx] + fb[idx];
        row[idx] = v[i];                    // write final y
        mx = fmaxf(mx, v[i]);
        if (idx == tg) tv = v[i];
    }
    // block-reduce max
    #pragma unroll
    for (int o = 32; o; o >>= 1) mx = fmaxf(mx, __shfl_xor(mx, o, 64));
    if (lane == 0) smx[wave] = mx;
    __syncthreads();
    mx = fmaxf(fmaxf(smx[0], smx[1]), fmaxf(smx[2], smx[3]));
    float s = 0.f;
    #pragma unroll
    for (int i = 0; i < 8; ++i) s += __expf(v[i] - mx);
    #pragma unroll
    for (int o = 32; o; o >>= 1) { s += __shfl_xor(s, o, 64); tv += __shfl_xor(tv, o, 64); }
    if (lane == 0) { ssum[wave] = s; stv[wave] = tv; }
    __syncthreads();
    if (t == 0) {
        float st = ssum[0] + ssum[1] + ssum[2] + ssum[3];
        float tt = stv[0] + stv[1] + stv[2] + stv[3];
        atomicAdd(out0, (mx + logf(st) - tt) * 0.125f);
    }
}

extern "C" void kernel_launch(void* const* d_in, const int* in_sizes, int n_in,
                              void* d_out, int out_size, void* d_ws, size_t ws_size,
                              hipStream_t stream) {
    const float* x   = (const float*)d_in[0];   // (B,L,D)
    const float* Uw  = (const float*)d_in[1];   // (Y,D)
    const float* fw  = (const float*)d_in[2];   // (Y,D)
    const float* fb  = (const float*)d_in[3];   // (Y,)
    const int*   tgt = (const int*)d_in[4];     // (B,)
    float* out = (float*)d_out;                 // [loss, y(B*Y)]

    char* ws = (char*)d_ws;
    u16*  x16  = (u16*)(ws);                          // B*L*D bf16 = 50,331,648 B (tiled)
    u16*  U16  = (u16*)(ws + 50331648);               // Y*D bf16   =  3,145,728 B (tiled)
    u16*  fw16 = (u16*)(ws + 53477376);               // Y*D bf16   =  3,145,728 B (tiled)
    float* rowsum = (float*)(ws + 56623104);          // B*Y fp32   =     65,536 B
    float* ynum   = (float*)(ws + 56688640);          // B*Y fp32   =     65,536 B

    // single prologue launch: tiled casts + zero rowsum/ynum/out
    prep_k<<<27648, 256, 0, stream>>>(x, Uw, fw, x16, U16, fw16, rowsum, out);

    // Fused S/G GEMM + exp + reductions: 4096 blocks (128l x 128y tiles),
    // L2-resident-weights order (R12 mapping)
    fused_k<<<(LL / 128) * (YY / 128) * BB, 256, 0, stream>>>(x16, U16, fw16, rowsum, ynum);

    ce_loss_k<<<BB, 256, 0, stream>>>(ynum, rowsum, fb, tgt, out, out + 1);
}